// Round 5
// baseline (139.133 us; speedup 1.0000x reference)
//
#include <hip/hip_runtime.h>
#include <cstdint>
#include <cstddef>

#define CCH   512
#define FSCOPE 27
#define HWSP  3136
#define NBATCH 16
#define NCOL  (NBATCH*HWSP)   // 50176

#define BN 32                 // cols per block; grid = 50176/32 = 1568

#define PI_F 3.14159265358979323846f

typedef __bf16 bf16x8 __attribute__((ext_vector_type(8)));
typedef float  f32x4  __attribute__((ext_vector_type(4)));

static __device__ __forceinline__ unsigned short f2bf(float f) {
  unsigned u = __builtin_bit_cast(unsigned, f);
  unsigned r = 0x7FFFu + ((u >> 16) & 1u);
  return (unsigned short)((u + r) >> 16);
}

// ---- kernel 1 (fused fk + inverse DFT, parallel over d):
__global__ __launch_bounds__(512)
void k_h2(const float* __restrict__ w, float* __restrict__ h) {
  __shared__ float red[8];
  const int d = blockIdx.x;
  const int m = threadIdx.x;

  float re = 1.0f, im = 0.0f;
  #pragma unroll
  for (int j = 0; j < FSCOPE; ++j) {
    int t = (m * (j - FSCOPE/2)) % CCH;
    if (t < 0) t += CCH;
    float ang = (2.0f * PI_F / CCH) * (float)t;
    float s, c;
    sincosf(ang, &s, &c);
    float wj = w[j];
    re -= wj * c;
    im += wj * s;
  }

  int t = (m * d) & (CCH - 1);
  float ang = (2.0f * PI_F / CCH) * (float)t;
  float s, c;
  sincosf(ang, &s, &c);
  float inv = 1.0f / (re * re + im * im);
  float term = (c * re + s * im) * inv;

  #pragma unroll
  for (int off = 32; off > 0; off >>= 1)
    term += __shfl_down(term, off, 64);

  const int lane = m & 63, wv = m >> 6;
  if (lane == 0) red[wv] = term;
  __syncthreads();
  if (m == 0) {
    float tot = 0.f;
    #pragma unroll
    for (int i = 0; i < 8; ++i) tot += red[i];
    h[d] = tot / (float)CCH;
  }
}

// ---- kernel 2: H[m][k] = bf16( h[(m-k) mod 512] ), row-major 512x512
__global__ void k_buildH(const float* __restrict__ h, unsigned short* __restrict__ Hm) {
  int m = blockIdx.x;
  for (int k = threadIdx.x; k < CCH; k += blockDim.x) {
    Hm[m*CCH + k] = f2bf(h[(m - k) & (CCH - 1)]);
  }
}

// ---- kernel 3: Y = H * X, barrier-free main loop.
// Block: 32 columns x all 512 channels. B (X cols) staged once in LDS
// (col-major bf16, XOR-swizzled); A (H) read per-fragment from global
// (512KB, L2-resident); 4 waves x 128 rows each; ONE barrier per block.
__global__ __launch_bounds__(256, 2)
void k_gemm(const float* __restrict__ X, const unsigned short* __restrict__ Hm,
            float* __restrict__ Y) {
  __shared__ __align__(16) unsigned char Bl[BN * 1024];  // [col][512k] bf16, swizzled

  const int tid  = threadIdx.x;
  const int lane = tid & 63;
  const int w    = tid >> 6;

  // XCD-aware swizzle (1568 = 8 * 196, bijective)
  int bid = blockIdx.x;
  int cpx = gridDim.x >> 3;
  int swz = (bid & 7) * cpx + (bid >> 3);
  const int j0 = swz * BN;
  const int nb = j0 / HWSP;          // 3136 % 32 == 0: block stays in one batch
  const int sb = j0 - nb * HWSP;
  const float* Xb = X + (size_t)nb * (CCH * (size_t)HWSP) + sb;

  // ---- stage B once: X[nb, 0:512, sb:sb+32] -> LDS col-major bf16
  // layout: addr(col, kchunk) = col*1024 + ((kchunk&7)^g(col))*16 + (kchunk>>3)*128
  // g(col) = (col&7) ^ (col>>3); kchunk = k/8 (8 bf16 = 16B per chunk)
  {
    const int cg = tid & 7;          // cols 4*cg .. 4*cg+3
    const int kg = tid >> 3;         // k rows kg*8..+8 within each 256-k pass
    #pragma unroll
    for (int pass = 0; pass < 2; ++pass) {
      float4 v[8];
      #pragma unroll
      for (int kk = 0; kk < 8; ++kk)
        v[kk] = *reinterpret_cast<const float4*>(
            Xb + (size_t)(pass * 256 + kg * 8 + kk) * HWSP + cg * 4);
      const int kchunk = pass * 32 + kg;
      #pragma unroll
      for (int c = 0; c < 4; ++c) {
        union { __bf16 b[8]; int4 q; } u;
        #pragma unroll
        for (int kk = 0; kk < 8; ++kk) {
          float f = (c==0) ? v[kk].x : (c==1) ? v[kk].y : (c==2) ? v[kk].z : v[kk].w;
          u.b[kk] = (__bf16)f;
        }
        int col = cg * 4 + c;
        int g = (col & 7) ^ (col >> 3);
        int addr = col * 1024 + (((kchunk & 7) ^ g) << 4) + ((kchunk >> 3) << 7);
        *reinterpret_cast<int4*>(Bl + addr) = u.q;
      }
    }
  }
  __syncthreads();   // the only barrier

  // ---- compute: wave w -> rows w*128 .. w*128+127
  const int r15 = lane & 15;
  const int kq  = lane >> 4;

  // B-frag LDS offsets: col = cb*16 + r15, k = kt*64 + ks*32 + kq*8
  // kchunk = kt*8 + ks*4 + kq  ->  addr = col*1024 + kt*128 + ((ks*4+kq)^g)*16
  int bOff[2][2];
  #pragma unroll
  for (int cb = 0; cb < 2; ++cb) {
    int col = cb * 16 + r15;
    int g = (col & 7) ^ (col >> 3);
    #pragma unroll
    for (int ks = 0; ks < 2; ++ks)
      bOff[cb][ks] = col * 1024 + (((ks * 4 + kq) ^ g) << 4);
  }

  // A base: element (w*128 + r15)*512 + kq*8 ; frag = + fm*16*512 + kt*64 + ks*32
  const unsigned short* aBase = Hm + (size_t)(w * 128 + r15) * CCH + kq * 8;

  f32x4 acc[8][2];
  #pragma unroll
  for (int i = 0; i < 8; ++i) {
    acc[i][0] = (f32x4){0.f, 0.f, 0.f, 0.f};
    acc[i][1] = (f32x4){0.f, 0.f, 0.f, 0.f};
  }

  #pragma unroll 2
  for (int kt = 0; kt < 8; ++kt) {
    bf16x8 bf[2][2];
    #pragma unroll
    for (int cb = 0; cb < 2; ++cb)
      #pragma unroll
      for (int ks = 0; ks < 2; ++ks)
        bf[cb][ks] = *reinterpret_cast<const bf16x8*>(Bl + bOff[cb][ks] + kt * 128);

    #pragma unroll
    for (int fm = 0; fm < 8; ++fm) {
      const unsigned short* ap = aBase + fm * (16 * CCH) + kt * 64;
      bf16x8 af0 = *reinterpret_cast<const bf16x8*>(ap);
      bf16x8 af1 = *reinterpret_cast<const bf16x8*>(ap + 32);
      acc[fm][0] = __builtin_amdgcn_mfma_f32_16x16x32_bf16(af0, bf[0][0], acc[fm][0], 0, 0, 0);
      acc[fm][0] = __builtin_amdgcn_mfma_f32_16x16x32_bf16(af1, bf[0][1], acc[fm][0], 0, 0, 0);
      acc[fm][1] = __builtin_amdgcn_mfma_f32_16x16x32_bf16(af0, bf[1][0], acc[fm][1], 0, 0, 0);
      acc[fm][1] = __builtin_amdgcn_mfma_f32_16x16x32_bf16(af1, bf[1][1], acc[fm][1], 0, 0, 0);
    }
  }

  // ---- epilogue: C/D layout col = lane&15, row = kq*4 + r  (m89/m91)
  float* Yn = Y + (size_t)nb * (CCH * (size_t)HWSP);
  #pragma unroll
  for (int fm = 0; fm < 8; ++fm) {
    int mrow = w * 128 + fm * 16 + kq * 4;
    #pragma unroll
    for (int cb = 0; cb < 2; ++cb) {
      float* yp = Yn + (size_t)mrow * HWSP + sb + cb * 16 + r15;
      #pragma unroll
      for (int r = 0; r < 4; ++r)
        yp[(size_t)r * HWSP] = acc[fm][cb][r];
    }
  }
}

extern "C" void kernel_launch(void* const* d_in, const int* in_sizes, int n_in,
                              void* d_out, int out_size, void* d_ws, size_t ws_size,
                              hipStream_t stream) {
  const float* X = (const float*)d_in[0];   // [16,512,56,56] f32
  const float* w = (const float*)d_in[1];   // [27] f32
  float* Y = (float*)d_out;

  float* h           = (float*)d_ws;                                // 2 KB
  unsigned short* Hm = (unsigned short*)((char*)d_ws + 4096);       // 512 KB

  k_h2    <<<CCH, 512, 0, stream>>>(w, h);
  k_buildH<<<CCH, 256, 0, stream>>>(h, Hm);

  k_gemm  <<<NCOL / BN, 256, 0, stream>>>(X, Hm, Y);
}

// Round 6
// 80.939 us; speedup vs baseline: 1.7190x; 1.7190x over previous
//
#include <hip/hip_runtime.h>
#include <cstdint>
#include <cstddef>

#define CCH   512
#define FSCOPE 27
#define HWSP  3136
#define NBATCH 16
#define NCOL  (NBATCH*HWSP)   // 50176

#define BM 128
#define BN 128
#define BK 64
#define NKT (CCH/BK)          // 8

#define PI_F 3.14159265358979323846f

typedef __bf16 bf16x8 __attribute__((ext_vector_type(8)));
typedef float  f32x4  __attribute__((ext_vector_type(4)));

static __device__ __forceinline__ unsigned short f2bf(float f) {
  unsigned u = __builtin_bit_cast(unsigned, f);
  unsigned r = 0x7FFFu + ((u >> 16) & 1u);
  return (unsigned short)((u + r) >> 16);
}

// ---- kernel 1 (fused fk + inverse DFT, parallel over d):
__global__ __launch_bounds__(512)
void k_h2(const float* __restrict__ w, float* __restrict__ h) {
  __shared__ float red[8];
  const int d = blockIdx.x;
  const int m = threadIdx.x;

  float re = 1.0f, im = 0.0f;
  #pragma unroll
  for (int j = 0; j < FSCOPE; ++j) {
    int t = (m * (j - FSCOPE/2)) % CCH;
    if (t < 0) t += CCH;
    float ang = (2.0f * PI_F / CCH) * (float)t;
    float s, c;
    sincosf(ang, &s, &c);
    float wj = w[j];
    re -= wj * c;
    im += wj * s;
  }

  int t = (m * d) & (CCH - 1);
  float ang = (2.0f * PI_F / CCH) * (float)t;
  float s, c;
  sincosf(ang, &s, &c);
  float inv = 1.0f / (re * re + im * im);
  float term = (c * re + s * im) * inv;

  #pragma unroll
  for (int off = 32; off > 0; off >>= 1)
    term += __shfl_down(term, off, 64);

  const int lane = m & 63, wv = m >> 6;
  if (lane == 0) red[wv] = term;
  __syncthreads();
  if (m == 0) {
    float tot = 0.f;
    #pragma unroll
    for (int i = 0; i < 8; ++i) tot += red[i];
    h[d] = tot / (float)CCH;
  }
}

// ---- kernel 2: H[m][k] = bf16( h[(m-k) mod 512] ), row-major 512x512
__global__ void k_buildH(const float* __restrict__ h, unsigned short* __restrict__ Hm) {
  int m = blockIdx.x;
  for (int k = threadIdx.x; k < CCH; k += blockDim.x) {
    Hm[m*CCH + k] = f2bf(h[(m - k) & (CCH - 1)]);
  }
}

// ---- kernel 3: Y = H * X, reg-staged double-buffered pipeline.
// grid = 4 m-tiles * 392 col-tiles = 1568 blocks, 256 threads (4 waves)
// LDS 64KB: A0@0, A1@16K, B0@32K, B1@48K -> 2 blocks/CU.
// Per iter: load(t+1)->regs ; compute(t) from LDS ; ds_write(t+1) ; barrier.
__global__ __launch_bounds__(256, 2)
void k_gemm(const float* __restrict__ X, const unsigned short* __restrict__ Hm,
            float* __restrict__ Y) {
  __shared__ __align__(16) unsigned char lds[65536];

  const int tid  = threadIdx.x;
  const int lane = tid & 63;
  const int w    = tid >> 6;

  // XCD-aware swizzle (1568 = 8 * 196, exact)
  int bid = blockIdx.x;
  int cpx = gridDim.x >> 3;
  int swz = (bid & 7) * cpx + (bid >> 3);
  const int tm = swz & 3;
  const int tc = swz >> 2;

  const int m0 = tm * BM;
  const int j0 = tc * BN;

  // ---- A staging map: thread -> 4 rows (ar+32i), chunk ac (16B of 8 bf16)
  // global: linear chunk ac; LDS: swizzled slot (ac ^ (m&7)) -> involution
  // consistent with the reader's (chunk ^ (m&7)).
  const int ar = tid >> 3;            // 0..31
  const int ac = tid & 7;             // 0..7
  const unsigned short* aSrcBase = Hm + (size_t)(m0 + ar) * CCH + ac * 8;
  const int aWr0 = ar * 128 + ((ac ^ (ar & 7)) << 4);  // +i*4096 for row ar+32i

  // ---- B staging map (identical to round 3): thread -> 4 cols x 8 k's
  const int fg = tid & 31;
  const int kg = tid >> 5;
  const int jb = j0 + fg*4;
  const int nb = jb / HWSP;           // 3136 % 4 == 0: float4 stays in batch
  const int sb = jb - nb * HWSP;
  const float* Xb = X + (size_t)nb * (CCH*(size_t)HWSP) + sb;

  int wrOff[4];
  #pragma unroll
  for (int c = 0; c < 4; ++c) {
    int col = fg*4 + c;
    int g = (col & 7) ^ ((col >> 3) & 7);
    wrOff[c] = col*128 + (((kg ^ g) & 7) << 4);
  }

  // ---- compute-side LDS offsets (round-3 verbatim)
  const int wr = w >> 1, wc = w & 1;   // wave -> 64x64 quadrant
  int aBase[4], aSw[4], bBase[4], bSw[4];
  #pragma unroll
  for (int fm = 0; fm < 4; ++fm) {
    int m = wr*64 + fm*16 + (lane & 15);
    aBase[fm] = m*128;
    aSw[fm]   = (m & 7) << 4;
  }
  #pragma unroll
  for (int fn = 0; fn < 4; ++fn) {
    int col = wc*64 + fn*16 + (lane & 15);
    bBase[fn] = col*128;
    bSw[fn]   = ((col & 7) ^ ((col >> 3) & 7)) << 4;
  }

  f32x4 acc[4][4];
  #pragma unroll
  for (int i = 0; i < 4; ++i)
    #pragma unroll
    for (int j = 0; j < 4; ++j)
      acc[i][j] = (f32x4){0.f, 0.f, 0.f, 0.f};

  // ---- prologue: stage tile 0 into buffers A0/B0
  {
    int4 av[4];
    float4 bv[8];
    #pragma unroll
    for (int i = 0; i < 4; ++i)
      av[i] = *reinterpret_cast<const int4*>(aSrcBase + (size_t)i * 32 * CCH);
    const float* Xk = Xb + (size_t)(kg * 8) * HWSP;
    #pragma unroll
    for (int kk = 0; kk < 8; ++kk)
      bv[kk] = *reinterpret_cast<const float4*>(Xk + (size_t)kk * HWSP);

    #pragma unroll
    for (int i = 0; i < 4; ++i)
      *reinterpret_cast<int4*>(lds + aWr0 + i * 4096) = av[i];
    #pragma unroll
    for (int c = 0; c < 4; ++c) {
      union { __bf16 h[8]; int4 v; } u;
      #pragma unroll
      for (int kk = 0; kk < 8; ++kk) {
        float f = (c==0) ? bv[kk].x : (c==1) ? bv[kk].y : (c==2) ? bv[kk].z : bv[kk].w;
        u.h[kk] = (__bf16)f;
      }
      *reinterpret_cast<int4*>(lds + 32768 + wrOff[c]) = u.v;
    }
  }
  __syncthreads();

  // ---- main loop
  #pragma unroll 2
  for (int kt = 0; kt < NKT; ++kt) {
    const int cur   = kt & 1;
    const int aoffC = cur * 16384;
    const int boffC = 32768 + cur * 16384;
    const int aoffN = 16384 - aoffC;
    const int boffN = 32768 + (16384 - aoffC);

    int4 av[4];
    float4 bv[8];
    const bool pf = (kt + 1 < NKT);
    if (pf) {
      const unsigned short* as = aSrcBase + (kt + 1) * BK;
      #pragma unroll
      for (int i = 0; i < 4; ++i)
        av[i] = *reinterpret_cast<const int4*>(as + (size_t)i * 32 * CCH);
      const float* Xk = Xb + (size_t)((kt + 1) * BK + kg * 8) * HWSP;
      #pragma unroll
      for (int kk = 0; kk < 8; ++kk)
        bv[kk] = *reinterpret_cast<const float4*>(Xk + (size_t)kk * HWSP);
    }

    // compute tile kt from CUR buffers
    #pragma unroll
    for (int ks = 0; ks < 2; ++ks) {
      const int kbyte = ks*64 + ((lane >> 4) << 4);
      bf16x8 af[4], bfr[4];
      #pragma unroll
      for (int fm = 0; fm < 4; ++fm)
        af[fm] = *reinterpret_cast<const bf16x8*>(lds + aoffC + aBase[fm] + (kbyte ^ aSw[fm]));
      #pragma unroll
      for (int fn = 0; fn < 4; ++fn)
        bfr[fn] = *reinterpret_cast<const bf16x8*>(lds + boffC + bBase[fn] + (kbyte ^ bSw[fn]));
      #pragma unroll
      for (int fm = 0; fm < 4; ++fm)
        #pragma unroll
        for (int fn = 0; fn < 4; ++fn)
          acc[fm][fn] = __builtin_amdgcn_mfma_f32_16x16x32_bf16(
              af[fm], bfr[fn], acc[fm][fn], 0, 0, 0);
    }

    // write tile kt+1 into NXT buffers (vmcnt wait for av/bv lands here,
    // covered by the MFMA cluster above)
    if (pf) {
      #pragma unroll
      for (int i = 0; i < 4; ++i)
        *reinterpret_cast<int4*>(lds + aoffN + aWr0 + i * 4096) = av[i];
      #pragma unroll
      for (int c = 0; c < 4; ++c) {
        union { __bf16 h[8]; int4 v; } u;
        #pragma unroll
        for (int kk = 0; kk < 8; ++kk) {
          float f = (c==0) ? bv[kk].x : (c==1) ? bv[kk].y : (c==2) ? bv[kk].z : bv[kk].w;
          u.h[kk] = (__bf16)f;
        }
        *reinterpret_cast<int4*>(lds + boffN + wrOff[c]) = u.v;
      }
    }

    __syncthreads();
  }

  // ---- epilogue: C/D layout col = lane&15, row = (lane>>4)*4 + r  (m89/m91)
  #pragma unroll
  for (int fn = 0; fn < 4; ++fn) {
    int colg = j0 + wc*64 + fn*16 + (lane & 15);
    int n = colg / HWSP;
    int s = colg - n * HWSP;
    float* Yb = Y + (size_t)n * (CCH*(size_t)HWSP) + s;
    #pragma unroll
    for (int fm = 0; fm < 4; ++fm) {
      int mrow = m0 + wr*64 + fm*16 + ((lane >> 4) << 2);
      #pragma unroll
      for (int r = 0; r < 4; ++r)
        Yb[(size_t)(mrow + r) * HWSP] = acc[fm][fn][r];
    }
  }
}

extern "C" void kernel_launch(void* const* d_in, const int* in_sizes, int n_in,
                              void* d_out, int out_size, void* d_ws, size_t ws_size,
                              hipStream_t stream) {
  const float* X = (const float*)d_in[0];   // [16,512,56,56] f32
  const float* w = (const float*)d_in[1];   // [27] f32
  float* Y = (float*)d_out;

  float* h           = (float*)d_ws;                                // 2 KB
  unsigned short* Hm = (unsigned short*)((char*)d_ws + 4096);       // 512 KB

  k_h2    <<<CCH, 512, 0, stream>>>(w, h);
  k_buildH<<<CCH, 256, 0, stream>>>(h, Hm);

  const int nblk = (CCH/BM) * (NCOL/BN);    // 4 * 392 = 1568
  k_gemm  <<<nblk, 256, 0, stream>>>(X, Hm, Y);
}

// Round 7
// 68.455 us; speedup vs baseline: 2.0325x; 1.1824x over previous
//
#include <hip/hip_runtime.h>
#include <cstdint>
#include <cstddef>

#define CCH   512
#define FSCOPE 27
#define HWSP  3136
#define NBATCH 16
#define NCOL  (NBATCH*HWSP)   // 50176

#define BM 256
#define BN 128
#define BK 64
#define NKT (CCH/BK)          // 8

#define PI_F 3.14159265358979323846f

typedef __bf16 bf16x8 __attribute__((ext_vector_type(8)));
typedef float  f32x4  __attribute__((ext_vector_type(4)));

static __device__ __forceinline__ unsigned short f2bf(float f) {
  unsigned u = __builtin_bit_cast(unsigned, f);
  unsigned r = 0x7FFFu + ((u >> 16) & 1u);
  return (unsigned short)((u + r) >> 16);
}

// ---- kernel 1 (fused fk + inverse DFT, parallel over d):
__global__ __launch_bounds__(512)
void k_h2(const float* __restrict__ w, float* __restrict__ h) {
  __shared__ float red[8];
  const int d = blockIdx.x;
  const int m = threadIdx.x;

  float re = 1.0f, im = 0.0f;
  #pragma unroll
  for (int j = 0; j < FSCOPE; ++j) {
    int t = (m * (j - FSCOPE/2)) % CCH;
    if (t < 0) t += CCH;
    float ang = (2.0f * PI_F / CCH) * (float)t;
    float s, c;
    sincosf(ang, &s, &c);
    float wj = w[j];
    re -= wj * c;
    im += wj * s;
  }

  int t = (m * d) & (CCH - 1);
  float ang = (2.0f * PI_F / CCH) * (float)t;
  float s, c;
  sincosf(ang, &s, &c);
  float inv = 1.0f / (re * re + im * im);
  float term = (c * re + s * im) * inv;

  #pragma unroll
  for (int off = 32; off > 0; off >>= 1)
    term += __shfl_down(term, off, 64);

  const int lane = m & 63, wv = m >> 6;
  if (lane == 0) red[wv] = term;
  __syncthreads();
  if (m == 0) {
    float tot = 0.f;
    #pragma unroll
    for (int i = 0; i < 8; ++i) tot += red[i];
    h[d] = tot / (float)CCH;
  }
}

// ---- kernel 2: H[m][k] = bf16( h[(m-k) mod 512] ), row-major 512x512
__global__ void k_buildH(const float* __restrict__ h, unsigned short* __restrict__ Hm) {
  int m = blockIdx.x;
  for (int k = threadIdx.x; k < CCH; k += blockDim.x) {
    Hm[m*CCH + k] = f2bf(h[(m - k) & (CCH - 1)]);
  }
}

// ---- kernel 3: Y = H * X — round-3 structure, BM=256 geometry.
// grid = 2 m-tiles * 392 col-tiles = 784 blocks, 512 threads (8 waves)
// 48KB LDS (32KB A + 16KB B), single-buffered, 2 barriers per K-step.
// X staged 2x total (was 4x at BM=128): slow-tier traffic -29%.
__global__ __launch_bounds__(512, 4)
void k_gemm(const float* __restrict__ X, const unsigned short* __restrict__ Hm,
            float* __restrict__ Y) {
  __shared__ __align__(16) unsigned char lds[BM*BK*2 + BN*BK*2]; // 32KB A + 16KB B

  const int tid  = threadIdx.x;
  const int lane = tid & 63;
  const int w    = tid >> 6;

  // XCD-aware swizzle (784 = 8 * 98, exact)
  int bid = blockIdx.x;
  int cpx = gridDim.x >> 3;
  int swz = (bid & 7) * cpx + (bid >> 3);
  const int tm = swz & 1;
  const int tc = swz >> 1;

  const int m0 = tm * BM;
  const int j0 = tc * BN;

  unsigned char* Al = lds;
  unsigned char* Bl = lds + BM*BK*2;

  // B staging mapping: thread -> 2 cols (float2) x 8 k's
  const int fg2 = tid & 63;      // col pair: cols 2*fg2, 2*fg2+1
  const int kg  = tid >> 6;      // k sub-block of 8 within BK (0..7)
  const int jb  = j0 + fg2*2;
  const int nb  = jb / HWSP;     // float2 never crosses batch (HWSP even)
  const int sb  = jb - nb * HWSP;
  const float* Xb = X + (size_t)nb * (CCH*(size_t)HWSP) + sb;

  // B swizzle: g(col) = (col&7) ^ ((col>>3)&7); slot = kq ^ g(col).
  int wrOff[2];
  #pragma unroll
  for (int c = 0; c < 2; ++c) {
    int col = fg2*2 + c;
    int g = (col & 7) ^ ((col >> 3) & 7);
    wrOff[c] = col*128 + (((kg ^ g) & 7) << 4);
  }

  const int wr = w >> 1, wc = w & 1;   // 8 waves: 4 row-quads x 2 col-halves
  int aBase[4], aSw[4], bBase[4], bSw[4];
  #pragma unroll
  for (int fm = 0; fm < 4; ++fm) {
    int m = wr*64 + fm*16 + (lane & 15);
    aBase[fm] = m*128;
    aSw[fm]   = (m & 7) << 4;
  }
  #pragma unroll
  for (int fn = 0; fn < 4; ++fn) {
    int col = wc*64 + fn*16 + (lane & 15);
    bBase[fn] = col*128;
    bSw[fn]   = ((col & 7) ^ ((col >> 3) & 7)) << 4;
  }

  f32x4 acc[4][4];
  #pragma unroll
  for (int i = 0; i < 4; ++i)
    #pragma unroll
    for (int j = 0; j < 4; ++j)
      acc[i][j] = (f32x4){0.f, 0.f, 0.f, 0.f};

  for (int kt = 0; kt < NKT; ++kt) {
    // B global loads (regs only, safe before barrier)
    float2 bv[8];
    const float* Xk = Xb + (size_t)(kt*BK + kg*8) * HWSP;
    #pragma unroll
    for (int kk = 0; kk < 8; ++kk)
      bv[kk] = *reinterpret_cast<const float2*>(Xk + (size_t)kk * HWSP);

    if (kt > 0) __syncthreads();   // previous tile fully consumed

    // A: global_load_lds, pre-swizzled source, linear LDS dest (rule #21)
    // 8 waves x 4 iters x 8 rows = 256 rows
    #pragma unroll
    for (int i = 0; i < 4; ++i) {
      int m0w = w*32 + i*8;                 // wave-uniform, 0..255
      int m   = m0w + (lane >> 3);
      int c   = lane & 7;
      const unsigned short* src =
          Hm + (size_t)(m0 + m) * CCH + kt*BK + 8*(c ^ (m & 7));
      unsigned char* dst = Al + m0w * 128;  // + lane*16 by HW
      __builtin_amdgcn_global_load_lds(
          (const __attribute__((address_space(1))) void*)src,
          (__attribute__((address_space(3))) void*)dst, 16, 0, 0);
    }

    // B: cvt fp32->bf16, swizzled ds_write_b128
    #pragma unroll
    for (int c = 0; c < 2; ++c) {
      union { __bf16 h[8]; int4 v; } u;
      #pragma unroll
      for (int kk = 0; kk < 8; ++kk) {
        float f = (c == 0) ? bv[kk].x : bv[kk].y;
        u.h[kk] = (__bf16)f;
      }
      *reinterpret_cast<int4*>(Bl + wrOff[c]) = u.v;
    }

    __syncthreads();   // A gload_lds drained + B writes visible

    #pragma unroll
    for (int ks = 0; ks < 2; ++ks) {
      const int kbyte = ks*64 + ((lane >> 4) << 4);
      bf16x8 af[4], bfr[4];
      #pragma unroll
      for (int fm = 0; fm < 4; ++fm)
        af[fm] = *reinterpret_cast<const bf16x8*>(Al + aBase[fm] + (kbyte ^ aSw[fm]));
      #pragma unroll
      for (int fn = 0; fn < 4; ++fn)
        bfr[fn] = *reinterpret_cast<const bf16x8*>(Bl + bBase[fn] + (kbyte ^ bSw[fn]));
      #pragma unroll
      for (int fm = 0; fm < 4; ++fm)
        #pragma unroll
        for (int fn = 0; fn < 4; ++fn)
          acc[fm][fn] = __builtin_amdgcn_mfma_f32_16x16x32_bf16(
              af[fm], bfr[fn], acc[fm][fn], 0, 0, 0);
    }
  }

  // epilogue: C/D layout col = lane&15, row = (lane>>4)*4 + r  (m89/m91)
  #pragma unroll
  for (int fn = 0; fn < 4; ++fn) {
    int colg = j0 + wc*64 + fn*16 + (lane & 15);
    int n = colg / HWSP;
    int s = colg - n * HWSP;
    float* Yb = Y + (size_t)n * (CCH*(size_t)HWSP) + s;
    #pragma unroll
    for (int fm = 0; fm < 4; ++fm) {
      int mrow = m0 + wr*64 + fm*16 + ((lane >> 4) << 2);
      #pragma unroll
      for (int r = 0; r < 4; ++r)
        Yb[(size_t)(mrow + r) * HWSP] = acc[fm][fn][r];
    }
  }
}

extern "C" void kernel_launch(void* const* d_in, const int* in_sizes, int n_in,
                              void* d_out, int out_size, void* d_ws, size_t ws_size,
                              hipStream_t stream) {
  const float* X = (const float*)d_in[0];   // [16,512,56,56] f32
  const float* w = (const float*)d_in[1];   // [27] f32
  float* Y = (float*)d_out;

  float* h           = (float*)d_ws;                                // 2 KB
  unsigned short* Hm = (unsigned short*)((char*)d_ws + 4096);       // 512 KB

  k_h2    <<<CCH, 512, 0, stream>>>(w, h);
  k_buildH<<<CCH, 256, 0, stream>>>(h, Hm);

  const int nblk = (CCH/BM) * (NCOL/BN);    // 2 * 392 = 784
  k_gemm  <<<nblk, 512, 0, stream>>>(X, Hm, Y);
}